// Round 9
// baseline (9893.822 us; speedup 1.0000x reference)
//
#include <hip/hip_runtime.h>
#include <cstdint>
#include <cstddef>

typedef unsigned long long u64;
typedef unsigned int u32;

#define NROWS 8192
#define DIN   1024
#define DOUT  4096
#define GAMMA 0.01618f
#define NC    640                 // exact candidate depth: 620 max suppressed + 10 + margin
#define RQ    2048                // u64 stride between candidate rows (16 KB = one H row)

// monotone order-preserving fp32 -> u32 (ascending); s>0 <=> key > 0x80000000
__device__ __forceinline__ u32 mono_key(float f) {
    u32 u = __float_as_uint(f);
    return (u & 0x80000000u) ? ~u : (u | 0x80000000u);
}
__device__ __forceinline__ u32 unmono_key(u32 u) {
    return (u & 0x80000000u) ? (u ^ 0x80000000u) : ~u;
}

// 64-lane max of a u64 via two 32-bit shuffles per step (validated r4-r8)
__device__ __forceinline__ u64 wave_max64(u64 x) {
#pragma unroll
    for (int off = 32; off >= 1; off >>= 1) {
        u32 lo = (u32)x, hi = (u32)(x >> 32);
        u32 olo = __shfl_xor(lo, off, 64);
        u32 ohi = __shfl_xor(hi, off, 64);
        u64 o = ((u64)ohi << 32) | olo;
        if (o > x) x = o;
    }
    return x;
}
__device__ __forceinline__ u64 shfl_u64(u64 x, int src) {
    u32 lo = __shfl((u32)x, src, 64);
    u32 hi = __shfl((u32)(x >> 32), src, 64);
    return ((u64)hi << 32) | lo;
}

// ---------------------------------------------------------------------------
// K1 (validated r5-r8): H = leaky_relu(X @ W^T + b), f64 accumulation.
// ---------------------------------------------------------------------------
__global__ __launch_bounds__(256)
void gemm_lrelu_f64acc(const float* __restrict__ X, const float* __restrict__ Wt,
                       const float* __restrict__ bias, float* __restrict__ H) {
    __shared__ float As[16][128];
    __shared__ float Bs[16][128];
    const int bx = blockIdx.x;
    const int by = blockIdx.y;
    const int tid = threadIdx.x;
    const int tx = tid & 15, ty = tid >> 4;
    const int m0 = by * 128, n0 = bx * 128;

    double acc[8][8];
#pragma unroll
    for (int i = 0; i < 8; i++)
#pragma unroll
        for (int j = 0; j < 8; j++) acc[i][j] = 0.0;

    for (int k0 = 0; k0 < DIN; k0 += 16) {
#pragma unroll
        for (int h = 0; h < 2; h++) {
            int id = tid + h * 256;
            int r  = id >> 2;
            int kc = id & 3;
            float4 a = *(const float4*)(X  + (size_t)(m0 + r) * DIN + k0 + kc * 4);
            As[kc * 4 + 0][r] = a.x; As[kc * 4 + 1][r] = a.y;
            As[kc * 4 + 2][r] = a.z; As[kc * 4 + 3][r] = a.w;
            float4 b = *(const float4*)(Wt + (size_t)(n0 + r) * DIN + k0 + kc * 4);
            Bs[kc * 4 + 0][r] = b.x; Bs[kc * 4 + 1][r] = b.y;
            Bs[kc * 4 + 2][r] = b.z; Bs[kc * 4 + 3][r] = b.w;
        }
        __syncthreads();
#pragma unroll
        for (int kk = 0; kk < 16; kk++) {
            float a[8], b[8];
            *(float4*)&a[0] = *(const float4*)&As[kk][ty * 4];
            *(float4*)&a[4] = *(const float4*)&As[kk][64 + ty * 4];
            *(float4*)&b[0] = *(const float4*)&Bs[kk][tx * 4];
            *(float4*)&b[4] = *(const float4*)&Bs[kk][64 + tx * 4];
#pragma unroll
            for (int i = 0; i < 8; i++)
#pragma unroll
                for (int j = 0; j < 8; j++)
                    acc[i][j] += (double)a[i] * (double)b[j];
        }
        __syncthreads();
    }

#pragma unroll
    for (int i = 0; i < 8; i++) {
        int mm = m0 + ((i < 4) ? (ty * 4 + i) : (64 + ty * 4 + i - 4));
        float* po = H + (size_t)mm * DOUT + n0;
#pragma unroll
        for (int j = 0; j < 8; j++) {
            int nn = (j < 4) ? (tx * 4 + j) : (64 + tx * 4 + j - 4);
            float h = (float)(acc[i][j] + (double)bias[n0 + nn]);
            h = (h >= 0.0f) ? h : 0.01f * h;
            po[nn] = h;
        }
    }
}

// ---------------------------------------------------------------------------
// K2 (validated r6-r8): per-row exact top-640 by (h desc, idx asc); bitonic-
// 4096 desc in LDS; first 640 mono-form keys written in place over row start.
// ---------------------------------------------------------------------------
__global__ __launch_bounds__(256)
void topk640_kernel(float* __restrict__ H) {
    __shared__ u64 skey[DOUT];     // 32 KB
    const int row = blockIdx.x;
    const int tid = threadIdx.x;
    float* hrow = H + (size_t)row * DOUT;

#pragma unroll
    for (int c = 0; c < 4; c++) {
        int j = c * 1024 + tid * 4;
        float4 v = *(const float4*)(hrow + j);
        skey[j + 0] = ((u64)mono_key(v.x) << 32) | (u32)(0xFFFFu - (u32)(j + 0));
        skey[j + 1] = ((u64)mono_key(v.y) << 32) | (u32)(0xFFFFu - (u32)(j + 1));
        skey[j + 2] = ((u64)mono_key(v.z) << 32) | (u32)(0xFFFFu - (u32)(j + 2));
        skey[j + 3] = ((u64)mono_key(v.w) << 32) | (u32)(0xFFFFu - (u32)(j + 3));
    }
    for (int size = 2; size <= DOUT; size <<= 1)
        for (int stride = size >> 1; stride > 0; stride >>= 1) {
            __syncthreads();
#pragma unroll 2
            for (int i = tid; i < DOUT / 2; i += 256) {
                int pos = 2 * i - (i & (stride - 1));
                u64 a = skey[pos], b = skey[pos + stride];
                bool up = (pos & size) == 0;
                if ((a < b) == up) { skey[pos] = b; skey[pos + stride] = a; }
            }
        }
    __syncthreads();
    u64* cand = (u64*)hrow;
    for (int j = tid; j < NC; j += 256) cand[j] = skey[j];
}

// ---------------------------------------------------------------------------
// K3: sequential scan, 1 block x 1 wave, software-pipelined recurrence.
// Per row m: the LDS gather for row m+1 issues at the TOP of row m (latency
// overlapped), then gets PATCHED with row m's <=10 winners (10 VALU cmps;
// patch value ls=m equals what the gather would see -> order-race-free).
// unsup = (t>=62) arithmetically (tbl saturates to exactly 1.0 at t=62).
// In-chunk exact top-10 with beater-merge (r7-validated rank logic); theta
// via ballot(rank==9) + 1 shfl (replaces 12-op wave_min64).
// Fallback (r6-validated): iterative 10 x wave_max64 over 640 candidates.
// ---------------------------------------------------------------------------
__global__ __launch_bounds__(64)
void scan_kernel(const u64* __restrict__ cand, float* __restrict__ out) {
    __shared__ int last_sel[DOUT];   // 16 KB
    const int lane = threadIdx.x;

    for (int j = lane; j < DOUT; j += 64) last_sel[j] = -100000;

    // lane i holds tbl[i]: tbl[0]=0, tbl[i]=min(tbl[i-1]+GAMMA,1) (exact fp32;
    // tbl[61]<1, tbl[62]=tbl[63]=1.0 exactly -> unsup <=> t>=62)
    float tbl_r = 0.0f;
    {
        float p = 0.0f;
        for (int i = 0; i < 64; i++) {
            if (i == lane) tbl_r = p;
            p = fminf(p + GAMMA, 1.0f);
        }
    }
    const u64 lmask_lt = (lane == 0) ? 0ull : ((1ull << lane) - 1ull);

    // pipeline state: rows m (A), m+1 (B); candidates prefetched 2 ahead
    u64 cA = cand[lane];                 // row 0 chunk0
    u64 kA = cand[64];                   // row 0 cand #64 (h-key bound)
    u64 cB = cand[RQ + lane];            // row 1
    u64 kB = cand[RQ + 64];
    int gA = last_sel[0xFFFF - (int)(cA & 0xFFFFu)];   // gather row 0 (exact)
    u32 Wid[10];
#pragma unroll
    for (int q = 0; q < 10; q++) Wid[q] = 0xFFFFFFFFu;

    for (int m = 0; m < NROWS; m++) {
        // prefetch row m+2 candidates (off the dependent chain)
        int rp = m + 2; if (rp >= NROWS) rp = 0;
        const u64 cC = cand[(size_t)rp * RQ + lane];
        const u64 kC = cand[(size_t)rp * RQ + 64];
        // issue gather for row m+1 now; patched with this row's winners later
        const int idB = 0xFFFF - (int)(cB & 0xFFFFu);
        const int gB = last_sel[idB];

        // ---- row m compute ----
        const int id = 0xFFFF - (int)(cA & 0xFFFFu);
        int ls = gA;
#pragma unroll
        for (int q = 0; q < 10; q++) if ((u32)id == Wid[q]) ls = m - 1;
        int t = m - ls - 1; if (t > 63) t = 63;
        const bool unsup = (t >= 62);
        const u64 mu = __ballot(unsup);          // independent of phi-shfl
        const float phi = __shfl(tbl_r, t);
        const float v = __uint_as_float(unmono_key((u32)(cA >> 32)));
        const float s = v * phi;
        const u64 skey = ((u64)mono_key(s) << 32) | (cA & 0xFFFFu);

        const int nu = __popcll(mu);
        const int prefix = __popcll(mu & lmask_lt);

        bool resolved = false, win = false;
        if (nu >= 10) {
            u64 um = mu;
#pragma unroll
            for (int q = 0; q < 9; q++) um &= um - 1;
            const int lane10 = __ffsll((long long)um) - 1;
            const u64 key10 = shfl_u64(skey, lane10);
            const u64 beat = __ballot(skey > key10) & ~mu;
            u64 theta;
            if (beat == 0ull) {
                win = unsup && (prefix < 10);
                theta = key10;
            } else {
                int myExtra = 0, myrank = 64;
                u64 bm = beat;
                while (bm) {
                    const int l = __ffsll((long long)bm) - 1;
                    bm &= bm - 1;
                    const u64 kb = shfl_u64(skey, l);
                    const u64 g = __ballot(skey > kb);
                    if (lane == l) myrank = __popcll(g);
                    myExtra += (kb > skey) ? 1 : 0;
                }
                const bool isbeat = (beat >> lane) & 1ull;
                const int rank = unsup ? (prefix + myExtra) : (isbeat ? myrank : 64);
                win = rank < 10;
                const u64 r9 = __ballot(rank == 9);      // exactly one lane
                const int l9 = __ffsll((long long)r9) - 1;
                theta = shfl_u64(skey, l9);
            }
            resolved = ((u32)(theta >> 32) > 0x80000000u) && (theta > kA);
        }

        bool sel; u32 mid;
        if (resolved) {
            sel = win; mid = (u32)id;
        } else {
            // ---- r6-validated exact fallback over up to 640 candidates ----
            const u64* crow = cand + (size_t)m * RQ;
            u64 tt[10];
            u64 key = skey, key2 = 0;
#pragma unroll 1
            for (int it = 0; it < 10; it++) {
                if (it > 0) {
                    u64 ck = crow[it * 64 + lane];
                    u32 hbits = unmono_key((u32)(ck >> 32));
                    int id2 = 0xFFFF - (int)(ck & 0xFFFFu);
                    int t2 = m - last_sel[id2] - 1; if (t2 > 63) t2 = 63;
                    float s2 = __uint_as_float(hbits) * __shfl(tbl_r, t2);
                    key = ((u64)mono_key(s2) << 32) | (ck & 0xFFFFu);
                    key2 = 0;
#pragma unroll
                    for (int rr = 0; rr < 10; rr++) if (lane == rr) key2 = tt[rr];
                }
#pragma unroll
                for (int rr = 0; rr < 10; rr++) {
                    u64 mx = (key > key2) ? key : key2;
                    u64 wm = wave_max64(mx);
                    if (key == wm)  key = 0;
                    if (key2 == wm) key2 = 0;
                    tt[rr] = wm;
                }
                if (it == 9) break;
                u32 thr = (u32)(tt[9] >> 32);
                u32 headhi = (u32)(crow[(it + 1) * 64] >> 32);
                if (thr > 0x80000000u && thr > headhi) break;
            }
            u64 wk = 0;
#pragma unroll
            for (int rr = 0; rr < 10; rr++) if (lane == rr) wk = tt[rr];
            sel = (lane < 10) && ((u32)(wk >> 32) > 0x80000000u);
            mid = (u32)(0xFFFF - (int)(wk & 0xFFFFu));
        }

        if (sel) {
            out[(size_t)m * DOUT + mid] = 1.0f;
            last_sel[mid] = m;           // for gathers >= 2 rows ahead
        }
        // publish winner ids for next row's patch (<=10, wave-uniform walk)
        u64 msk = __ballot(sel);
#pragma unroll
        for (int q = 0; q < 10; q++) {
            u32 wq = 0xFFFFFFFFu;
            if (msk) {
                const int l = __ffsll((long long)msk) - 1;
                wq = (u32)__shfl((int)mid, l);
                msk &= msk - 1;
            }
            Wid[q] = wq;
        }

        // rotate pipeline
        cA = cB; kA = kB; gA = gB;
        cB = cC; kB = kC;
    }
}

// ---------------------------------------------------------------------------
extern "C" void kernel_launch(void* const* d_in, const int* in_sizes, int n_in,
                              void* d_out, int out_size, void* d_ws, size_t ws_size,
                              hipStream_t stream) {
    const float* X  = (const float*)d_in[0];   // 8192 x 1024 f32
    const float* Wt = (const float*)d_in[1];   // 4096 x 1024 f32
    const float* b  = (const float*)d_in[2];   // 4096 f32
    // d_in[3] = k == 10 (beacon-verified)
    float* out = (float*)d_out;
    float* H   = (float*)d_ws;                 // 128 MB (beacon-verified)
    (void)in_sizes; (void)n_in; (void)out_size; (void)ws_size;

    gemm_lrelu_f64acc<<<dim3(32, 64), 256, 0, stream>>>(X, Wt, b, H);
    topk640_kernel<<<dim3(NROWS), 256, 0, stream>>>(H);
    hipMemsetAsync(d_out, 0, (size_t)NROWS * DOUT * sizeof(float), stream);
    scan_kernel<<<dim3(1), 64, 0, stream>>>((const u64*)H, out);
}

// Round 10
// 4874.195 us; speedup vs baseline: 2.0298x; 2.0298x over previous
//
#include <hip/hip_runtime.h>
#include <cstdint>
#include <cstddef>

typedef unsigned long long u64;
typedef unsigned int u32;

#define NROWS 8192
#define DIN   1024
#define DOUT  4096
#define GAMMA 0.01618f
#define NC    640                 // exact candidate depth: 620 max suppressed + 10 + margin
#define RQ    2048                // u64 stride between candidate rows (16 KB = one H row)
#define BATCH 8                   // speculative rows per batch = waves per block

// monotone order-preserving fp32 -> u32 (ascending); s>0 <=> key > 0x80000000
__device__ __forceinline__ u32 mono_key(float f) {
    u32 u = __float_as_uint(f);
    return (u & 0x80000000u) ? ~u : (u | 0x80000000u);
}
__device__ __forceinline__ u32 unmono_key(u32 u) {
    return (u & 0x80000000u) ? (u ^ 0x80000000u) : ~u;
}

// 64-lane max of a u64 via two 32-bit shuffles per step (validated r4-r8)
__device__ __forceinline__ u64 wave_max64(u64 x) {
#pragma unroll
    for (int off = 32; off >= 1; off >>= 1) {
        u32 lo = (u32)x, hi = (u32)(x >> 32);
        u32 olo = __shfl_xor(lo, off, 64);
        u32 ohi = __shfl_xor(hi, off, 64);
        u64 o = ((u64)ohi << 32) | olo;
        if (o > x) x = o;
    }
    return x;
}
__device__ __forceinline__ u64 shfl_u64(u64 x, int src) {
    u32 lo = __shfl((u32)x, src, 64);
    u32 hi = __shfl((u32)(x >> 32), src, 64);
    return ((u64)hi << 32) | lo;
}

// ---------------------------------------------------------------------------
// K1 (validated r5-r9): H = leaky_relu(X @ W^T + b), f64 accumulation.
// ---------------------------------------------------------------------------
__global__ __launch_bounds__(256)
void gemm_lrelu_f64acc(const float* __restrict__ X, const float* __restrict__ Wt,
                       const float* __restrict__ bias, float* __restrict__ H) {
    __shared__ float As[16][128];
    __shared__ float Bs[16][128];
    const int bx = blockIdx.x;
    const int by = blockIdx.y;
    const int tid = threadIdx.x;
    const int tx = tid & 15, ty = tid >> 4;
    const int m0 = by * 128, n0 = bx * 128;

    double acc[8][8];
#pragma unroll
    for (int i = 0; i < 8; i++)
#pragma unroll
        for (int j = 0; j < 8; j++) acc[i][j] = 0.0;

    for (int k0 = 0; k0 < DIN; k0 += 16) {
#pragma unroll
        for (int h = 0; h < 2; h++) {
            int id = tid + h * 256;
            int r  = id >> 2;
            int kc = id & 3;
            float4 a = *(const float4*)(X  + (size_t)(m0 + r) * DIN + k0 + kc * 4);
            As[kc * 4 + 0][r] = a.x; As[kc * 4 + 1][r] = a.y;
            As[kc * 4 + 2][r] = a.z; As[kc * 4 + 3][r] = a.w;
            float4 b = *(const float4*)(Wt + (size_t)(n0 + r) * DIN + k0 + kc * 4);
            Bs[kc * 4 + 0][r] = b.x; Bs[kc * 4 + 1][r] = b.y;
            Bs[kc * 4 + 2][r] = b.z; Bs[kc * 4 + 3][r] = b.w;
        }
        __syncthreads();
#pragma unroll
        for (int kk = 0; kk < 16; kk++) {
            float a[8], b[8];
            *(float4*)&a[0] = *(const float4*)&As[kk][ty * 4];
            *(float4*)&a[4] = *(const float4*)&As[kk][64 + ty * 4];
            *(float4*)&b[0] = *(const float4*)&Bs[kk][tx * 4];
            *(float4*)&b[4] = *(const float4*)&Bs[kk][64 + tx * 4];
#pragma unroll
            for (int i = 0; i < 8; i++)
#pragma unroll
                for (int j = 0; j < 8; j++)
                    acc[i][j] += (double)a[i] * (double)b[j];
        }
        __syncthreads();
    }

#pragma unroll
    for (int i = 0; i < 8; i++) {
        int mm = m0 + ((i < 4) ? (ty * 4 + i) : (64 + ty * 4 + i - 4));
        float* po = H + (size_t)mm * DOUT + n0;
#pragma unroll
        for (int j = 0; j < 8; j++) {
            int nn = (j < 4) ? (tx * 4 + j) : (64 + tx * 4 + j - 4);
            float h = (float)(acc[i][j] + (double)bias[n0 + nn]);
            h = (h >= 0.0f) ? h : 0.01f * h;
            po[nn] = h;
        }
    }
}

// ---------------------------------------------------------------------------
// K2 (validated r6-r9): per-row exact top-640 by (h desc, idx asc); bitonic-
// 4096 desc in LDS; first 640 mono-form keys written in place over row start.
// ---------------------------------------------------------------------------
__global__ __launch_bounds__(256)
void topk640_kernel(float* __restrict__ H) {
    __shared__ u64 skey[DOUT];     // 32 KB
    const int row = blockIdx.x;
    const int tid = threadIdx.x;
    float* hrow = H + (size_t)row * DOUT;

#pragma unroll
    for (int c = 0; c < 4; c++) {
        int j = c * 1024 + tid * 4;
        float4 v = *(const float4*)(hrow + j);
        skey[j + 0] = ((u64)mono_key(v.x) << 32) | (u32)(0xFFFFu - (u32)(j + 0));
        skey[j + 1] = ((u64)mono_key(v.y) << 32) | (u32)(0xFFFFu - (u32)(j + 1));
        skey[j + 2] = ((u64)mono_key(v.z) << 32) | (u32)(0xFFFFu - (u32)(j + 2));
        skey[j + 3] = ((u64)mono_key(v.w) << 32) | (u32)(0xFFFFu - (u32)(j + 3));
    }
    for (int size = 2; size <= DOUT; size <<= 1)
        for (int stride = size >> 1; stride > 0; stride >>= 1) {
            __syncthreads();
#pragma unroll 2
            for (int i = tid; i < DOUT / 2; i += 256) {
                int pos = 2 * i - (i & (stride - 1));
                u64 a = skey[pos], b = skey[pos + stride];
                bool up = (pos & size) == 0;
                if ((a < b) == up) { skey[pos] = b; skey[pos + stride] = a; }
            }
        }
    __syncthreads();
    u64* cand = (u64*)hrow;
    for (int j = tid; j < NC; j += 256) cand[j] = skey[j];
}

// ---------------------------------------------------------------------------
// r8-validated per-row exact top-10 (fast path + beater-merge + fallback),
// factored as a wave-scoped device function. sel/mid: this lane's winner.
// ---------------------------------------------------------------------------
__device__ __forceinline__ void row_top10(
    int m, u64 c, u64 k64, const u64* __restrict__ crow,
    const int* last_sel, float tbl_r, int lane, u64 lmask_lt,
    bool& sel, u32& mid)
{
    const int id = 0xFFFF - (int)(c & 0xFFFFu);
    int t = m - last_sel[id] - 1; if (t > 63) t = 63;
    const bool unsup = (t >= 62);            // tbl saturates to exactly 1 at 62
    const u64 mu = __ballot(unsup);
    const float phi = __shfl(tbl_r, t);
    const float v = __uint_as_float(unmono_key((u32)(c >> 32)));
    const float s = v * phi;
    const u64 skey = ((u64)mono_key(s) << 32) | (c & 0xFFFFu);
    const int nu = __popcll(mu);
    const int prefix = __popcll(mu & lmask_lt);

    bool resolved = false, win = false;
    if (nu >= 10) {
        u64 um = mu;
#pragma unroll
        for (int q = 0; q < 9; q++) um &= um - 1;
        const int lane10 = __ffsll((long long)um) - 1;
        const u64 key10 = shfl_u64(skey, lane10);
        const u64 beat = __ballot(skey > key10) & ~mu;
        u64 theta;
        if (beat == 0ull) {
            win = unsup && (prefix < 10);
            theta = key10;
        } else {
            int myExtra = 0, myrank = 64;
            u64 bm = beat;
            while (bm) {
                const int l = __ffsll((long long)bm) - 1;
                bm &= bm - 1;
                const u64 kb = shfl_u64(skey, l);
                const u64 g = __ballot(skey > kb);
                if (lane == l) myrank = __popcll(g);
                myExtra += (kb > skey) ? 1 : 0;
            }
            const bool isbeat = (beat >> lane) & 1ull;
            const int rank = unsup ? (prefix + myExtra) : (isbeat ? myrank : 64);
            win = rank < 10;
            const u64 r9 = __ballot(rank == 9);
            const int l9 = __ffsll((long long)r9) - 1;
            theta = shfl_u64(skey, l9);
        }
        resolved = ((u32)(theta >> 32) > 0x80000000u) && (theta > k64);
    }

    if (resolved) {
        sel = win; mid = (u32)id;
        return;
    }
    // ---- r6-validated exact fallback over up to 640 candidates ----
    u64 tt[10];
    u64 key = skey, key2 = 0;
#pragma unroll 1
    for (int it = 0; it < 10; it++) {
        if (it > 0) {
            u64 ck = crow[it * 64 + lane];
            u32 hbits = unmono_key((u32)(ck >> 32));
            int id2 = 0xFFFF - (int)(ck & 0xFFFFu);
            int t2 = m - last_sel[id2] - 1; if (t2 > 63) t2 = 63;
            float s2 = __uint_as_float(hbits) * __shfl(tbl_r, t2);
            key = ((u64)mono_key(s2) << 32) | (ck & 0xFFFFu);
            key2 = 0;
#pragma unroll
            for (int rr = 0; rr < 10; rr++) if (lane == rr) key2 = tt[rr];
        }
#pragma unroll
        for (int rr = 0; rr < 10; rr++) {
            u64 mx = (key > key2) ? key : key2;
            u64 wm = wave_max64(mx);
            if (key == wm)  key = 0;
            if (key2 == wm) key2 = 0;
            tt[rr] = wm;
        }
        if (it == 9) break;
        u32 thr = (u32)(tt[9] >> 32);
        u32 headhi = (u32)(crow[(it + 1) * 64] >> 32);
        if (thr > 0x80000000u && thr > headhi) break;
    }
    u64 wk = 0;
#pragma unroll
    for (int rr = 0; rr < 10; rr++) if (lane == rr) wk = tt[rr];
    sel = (lane < 10) && ((u32)(wk >> 32) > 0x80000000u);
    mid = (u32)(0xFFFF - (int)(wk & 0xFFFFu));
}

// ---------------------------------------------------------------------------
// K3: speculative-batch sequential scan. 1 block x 8 waves (512 threads).
// Spec phase: wave w computes row m0+w's top-10 from the batch-start
// last_sel snapshot (read-only). Exact-validity rule (see analysis): spec
// result is correct iff none of its positive winners was selected earlier in
// the batch -- detected by re-gathering last_sel[id] >= m0 in the fixup.
// Fixup phase (wave 0, serial in-order): validate each row; accept (write
// out + last_sel) or recompute exactly with the r8 routine on current state.
// ---------------------------------------------------------------------------
__global__ __launch_bounds__(512)
void scan_kernel(const u64* __restrict__ cand, float* __restrict__ out) {
    __shared__ int last_sel[DOUT];           // 16 KB
    __shared__ u32 specw[BATCH][16];         // spec winner ids (0xFFFFFFFF pad)
    __shared__ u64 chunk0[BATCH][64];        // spec chunk-0 backup (4 KB)
    __shared__ u64 k64s[BATCH];
    const int tid  = threadIdx.x;
    const int lane = tid & 63;
    const int w    = tid >> 6;

    for (int j = tid; j < DOUT; j += 512) last_sel[j] = -100000;

    float tbl_r = 0.0f;                      // lane i holds tbl[i]
    {
        float p = 0.0f;
        for (int i = 0; i < 64; i++) {
            if (i == lane) tbl_r = p;
            p = fminf(p + GAMMA, 1.0f);
        }
    }
    const u64 lmask_lt = (lane == 0) ? 0ull : ((1ull << lane) - 1ull);
    __syncthreads();

    // prefetch batch 0
    u64 cpre = cand[(size_t)w * RQ + lane];
    u64 kpre = cand[(size_t)w * RQ + 64];

    for (int m0 = 0; m0 < NROWS; m0 += BATCH) {
        const int m = m0 + w;
        const u64 c  = cpre;
        const u64 kk = kpre;
        // prefetch next batch (latency hidden under spec+fixup)
        int mp = m + BATCH; if (mp >= NROWS) mp = w;
        cpre = cand[(size_t)mp * RQ + lane];
        kpre = cand[(size_t)mp * RQ + 64];

        // ---- spec phase: all 8 waves in parallel on snapshot state ----
        bool sel; u32 mid;
        row_top10(m, c, kk, cand + (size_t)m * RQ, last_sel, tbl_r, lane,
                  lmask_lt, sel, mid);

        if (lane < 16) specw[w][lane] = 0xFFFFFFFFu;
        const u64 smask = __ballot(sel);
        const int slot = __popcll(smask & lmask_lt);
        if (sel) specw[w][slot] = mid;
        chunk0[w][lane] = c;
        if (lane == 0) k64s[w] = kk;
        __syncthreads();

        // ---- fixup phase: wave 0, serial in row order ----
        if (w == 0) {
            for (int i = 0; i < BATCH; i++) {
                const int mi = m0 + i;
                const u32 sid = (lane < 10) ? specw[i][lane] : 0xFFFFFFFFu;
                const bool has = (sid != 0xFFFFFFFFu);
                const int ls2 = has ? last_sel[sid] : -100000;
                const u64 stale = __ballot(has && (ls2 >= m0));
                if (stale == 0ull) {
                    if (has) {
                        out[(size_t)mi * DOUT + sid] = 1.0f;
                        last_sel[sid] = mi;
                    }
                } else {
                    bool s2; u32 mid2;
                    row_top10(mi, chunk0[i][lane], k64s[i],
                              cand + (size_t)mi * RQ, last_sel, tbl_r, lane,
                              lmask_lt, s2, mid2);
                    if (s2) {
                        out[(size_t)mi * DOUT + mid2] = 1.0f;
                        last_sel[mid2] = mi;
                    }
                }
            }
        }
        __syncthreads();
    }
}

// ---------------------------------------------------------------------------
extern "C" void kernel_launch(void* const* d_in, const int* in_sizes, int n_in,
                              void* d_out, int out_size, void* d_ws, size_t ws_size,
                              hipStream_t stream) {
    const float* X  = (const float*)d_in[0];   // 8192 x 1024 f32
    const float* Wt = (const float*)d_in[1];   // 4096 x 1024 f32
    const float* b  = (const float*)d_in[2];   // 4096 f32
    // d_in[3] = k == 10 (beacon-verified)
    float* out = (float*)d_out;
    float* H   = (float*)d_ws;                 // 128 MB (beacon-verified)
    (void)in_sizes; (void)n_in; (void)out_size; (void)ws_size;

    gemm_lrelu_f64acc<<<dim3(32, 64), 256, 0, stream>>>(X, Wt, b, H);
    topk640_kernel<<<dim3(NROWS), 256, 0, stream>>>(H);
    hipMemsetAsync(d_out, 0, (size_t)NROWS * DOUT * sizeof(float), stream);
    scan_kernel<<<dim3(1), 512, 0, stream>>>((const u64*)H, out);
}

// Round 11
// 3849.804 us; speedup vs baseline: 2.5700x; 1.2661x over previous
//
#include <hip/hip_runtime.h>
#include <cstdint>
#include <cstddef>

typedef unsigned long long u64;
typedef unsigned int u32;

#define NROWS 8192
#define DIN   1024
#define DOUT  4096
#define GAMMA 0.01618f
#define NC    640                 // exact candidate depth: 620 max suppressed + 10 + margin
#define RQ    2048                // u64 stride between candidate rows (16 KB = one H row)
#define BATCH 8                   // speculative rows per batch = waves per block

// monotone order-preserving fp32 -> u32 (ascending); s>0 <=> key > 0x80000000
__device__ __forceinline__ u32 mono_key(float f) {
    u32 u = __float_as_uint(f);
    return (u & 0x80000000u) ? ~u : (u | 0x80000000u);
}
__device__ __forceinline__ u32 unmono_key(u32 u) {
    return (u & 0x80000000u) ? (u ^ 0x80000000u) : ~u;
}

// 64-lane max of a u64 via two 32-bit shuffles per step (validated r4-r10)
__device__ __forceinline__ u64 wave_max64(u64 x) {
#pragma unroll
    for (int off = 32; off >= 1; off >>= 1) {
        u32 lo = (u32)x, hi = (u32)(x >> 32);
        u32 olo = __shfl_xor(lo, off, 64);
        u32 ohi = __shfl_xor(hi, off, 64);
        u64 o = ((u64)ohi << 32) | olo;
        if (o > x) x = o;
    }
    return x;
}
__device__ __forceinline__ u64 shfl_u64(u64 x, int src) {
    u32 lo = __shfl((u32)x, src, 64);
    u32 hi = __shfl((u32)(x >> 32), src, 64);
    return ((u64)hi << 32) | lo;
}

// ---------------------------------------------------------------------------
// K1 (validated r5-r10): H = leaky_relu(X @ W^T + b), f64 accumulation.
// ---------------------------------------------------------------------------
__global__ __launch_bounds__(256)
void gemm_lrelu_f64acc(const float* __restrict__ X, const float* __restrict__ Wt,
                       const float* __restrict__ bias, float* __restrict__ H) {
    __shared__ float As[16][128];
    __shared__ float Bs[16][128];
    const int bx = blockIdx.x;
    const int by = blockIdx.y;
    const int tid = threadIdx.x;
    const int tx = tid & 15, ty = tid >> 4;
    const int m0 = by * 128, n0 = bx * 128;

    double acc[8][8];
#pragma unroll
    for (int i = 0; i < 8; i++)
#pragma unroll
        for (int j = 0; j < 8; j++) acc[i][j] = 0.0;

    for (int k0 = 0; k0 < DIN; k0 += 16) {
#pragma unroll
        for (int h = 0; h < 2; h++) {
            int id = tid + h * 256;
            int r  = id >> 2;
            int kc = id & 3;
            float4 a = *(const float4*)(X  + (size_t)(m0 + r) * DIN + k0 + kc * 4);
            As[kc * 4 + 0][r] = a.x; As[kc * 4 + 1][r] = a.y;
            As[kc * 4 + 2][r] = a.z; As[kc * 4 + 3][r] = a.w;
            float4 b = *(const float4*)(Wt + (size_t)(n0 + r) * DIN + k0 + kc * 4);
            Bs[kc * 4 + 0][r] = b.x; Bs[kc * 4 + 1][r] = b.y;
            Bs[kc * 4 + 2][r] = b.z; Bs[kc * 4 + 3][r] = b.w;
        }
        __syncthreads();
#pragma unroll
        for (int kk = 0; kk < 16; kk++) {
            float a[8], b[8];
            *(float4*)&a[0] = *(const float4*)&As[kk][ty * 4];
            *(float4*)&a[4] = *(const float4*)&As[kk][64 + ty * 4];
            *(float4*)&b[0] = *(const float4*)&Bs[kk][tx * 4];
            *(float4*)&b[4] = *(const float4*)&Bs[kk][64 + tx * 4];
#pragma unroll
            for (int i = 0; i < 8; i++)
#pragma unroll
                for (int j = 0; j < 8; j++)
                    acc[i][j] += (double)a[i] * (double)b[j];
        }
        __syncthreads();
    }

#pragma unroll
    for (int i = 0; i < 8; i++) {
        int mm = m0 + ((i < 4) ? (ty * 4 + i) : (64 + ty * 4 + i - 4));
        float* po = H + (size_t)mm * DOUT + n0;
#pragma unroll
        for (int j = 0; j < 8; j++) {
            int nn = (j < 4) ? (tx * 4 + j) : (64 + tx * 4 + j - 4);
            float h = (float)(acc[i][j] + (double)bias[n0 + nn]);
            h = (h >= 0.0f) ? h : 0.01f * h;
            po[nn] = h;
        }
    }
}

// ---------------------------------------------------------------------------
// K2 v2: per-row exact top-640 via 12-bit histogram select + bitonic-1024.
// hist bins = top 12 bits of mono key; threshold bin b = lowest bin such that
// count(bins >= b) >= 640 -> compacted set (~700) is a SUPERSET of the true
// top-640 by (h desc, idx asc) (ties share a bin, all included). Full sort of
// the 1024-padded compacted set gives the exact first 640. Output format
// byte-identical to r6-r10: u64 (mono<<32)|(0xFFFF-idx) at the row start.
// ---------------------------------------------------------------------------
__global__ __launch_bounds__(256)
void topk640_kernel(float* __restrict__ H) {
    __shared__ u32 skey[DOUT];      // 16 KB
    __shared__ int hist[DOUT];      // 16 KB (4096 bins)
    __shared__ u64 scand[1024];     // 8 KB
    __shared__ int seg[256];
    __shared__ int s_b, s_cnt;
    const int row = blockIdx.x;
    const int tid = threadIdx.x;
    float* hrow = H + (size_t)row * DOUT;

#pragma unroll
    for (int c = 0; c < 4; c++) {
        int j = c * 1024 + tid * 4;
        float4 v = *(const float4*)(hrow + j);
        skey[j + 0] = mono_key(v.x); skey[j + 1] = mono_key(v.y);
        skey[j + 2] = mono_key(v.z); skey[j + 3] = mono_key(v.w);
    }
#pragma unroll
    for (int c = 0; c < 16; c++) hist[c * 256 + tid] = 0;
    if (tid == 0) s_cnt = 0;
    __syncthreads();
#pragma unroll
    for (int c = 0; c < 4; c++) {
        int j = c * 1024 + tid * 4;
        atomicAdd(&hist[skey[j + 0] >> 20], 1);
        atomicAdd(&hist[skey[j + 1] >> 20], 1);
        atomicAdd(&hist[skey[j + 2] >> 20], 1);
        atomicAdd(&hist[skey[j + 3] >> 20], 1);
    }
    __syncthreads();
    {
        int ssum = 0;
#pragma unroll
        for (int i = 0; i < 16; i++) ssum += hist[tid * 16 + i];
        seg[tid] = ssum;
    }
    __syncthreads();
    if (tid == 0) {
        int cum = 0, ts;
        for (ts = 255; ts >= 0; ts--) {
            if (cum + seg[ts] >= NC) break;
            cum += seg[ts];
        }
        int b = 0;
        if (ts >= 0) {
            int bin;
            for (bin = ts * 16 + 15; bin >= ts * 16; bin--) {
                cum += hist[bin];
                if (cum >= NC) break;
            }
            b = (bin < ts * 16) ? ts * 16 : bin;
        }
        s_b = b;
    }
    __syncthreads();
    const int b = s_b;
#pragma unroll
    for (int c = 0; c < 4; c++) {
        int jb = c * 1024 + tid * 4;
#pragma unroll
        for (int q = 0; q < 4; q++) {
            int j = jb + q;
            u32 k = skey[j];
            if ((int)(k >> 20) >= b) {
                int pos = atomicAdd(&s_cnt, 1);
                if (pos < 1024)
                    scand[pos] = ((u64)k << 32) | (u32)(0xFFFFu - (u32)j);
            }
        }
    }
    __syncthreads();
    int C = s_cnt; if (C > 1024) C = 1024;
    for (int j = C + tid; j < 1024; j += 256) scand[j] = 0;  // pad sorts last
    // bitonic sort 1024, descending (same comparator as r6-r10)
    for (int size = 2; size <= 1024; size <<= 1)
        for (int stride = size >> 1; stride > 0; stride >>= 1) {
            __syncthreads();
#pragma unroll 2
            for (int i = tid; i < 512; i += 256) {
                int pos = 2 * i - (i & (stride - 1));
                u64 a = scand[pos], bb = scand[pos + stride];
                bool up = (pos & size) == 0;
                if ((a < bb) == up) { scand[pos] = bb; scand[pos + stride] = a; }
            }
        }
    __syncthreads();
    u64* cand = (u64*)hrow;
    for (int j = tid; j < NC; j += 256) cand[j] = scand[j];
}

// ---------------------------------------------------------------------------
// r8-validated per-row exact top-10 (fast path + beater-merge + fallback).
// ---------------------------------------------------------------------------
__device__ __forceinline__ void row_top10(
    int m, u64 c, u64 k64, const u64* __restrict__ crow,
    const int* last_sel, float tbl_r, int lane, u64 lmask_lt,
    bool& sel, u32& mid)
{
    const int id = 0xFFFF - (int)(c & 0xFFFFu);
    int t = m - last_sel[id] - 1; if (t > 63) t = 63;
    const bool unsup = (t >= 62);            // tbl saturates to exactly 1 at 62
    const u64 mu = __ballot(unsup);
    const float phi = __shfl(tbl_r, t);
    const float v = __uint_as_float(unmono_key((u32)(c >> 32)));
    const float s = v * phi;
    const u64 skey = ((u64)mono_key(s) << 32) | (c & 0xFFFFu);
    const int nu = __popcll(mu);
    const int prefix = __popcll(mu & lmask_lt);

    bool resolved = false, win = false;
    if (nu >= 10) {
        u64 um = mu;
#pragma unroll
        for (int q = 0; q < 9; q++) um &= um - 1;
        const int lane10 = __ffsll((long long)um) - 1;
        const u64 key10 = shfl_u64(skey, lane10);
        const u64 beat = __ballot(skey > key10) & ~mu;
        u64 theta;
        if (beat == 0ull) {
            win = unsup && (prefix < 10);
            theta = key10;
        } else {
            int myExtra = 0, myrank = 64;
            u64 bm = beat;
            while (bm) {
                const int l = __ffsll((long long)bm) - 1;
                bm &= bm - 1;
                const u64 kb = shfl_u64(skey, l);
                const u64 g = __ballot(skey > kb);
                if (lane == l) myrank = __popcll(g);
                myExtra += (kb > skey) ? 1 : 0;
            }
            const bool isbeat = (beat >> lane) & 1ull;
            const int rank = unsup ? (prefix + myExtra) : (isbeat ? myrank : 64);
            win = rank < 10;
            const u64 r9 = __ballot(rank == 9);
            const int l9 = __ffsll((long long)r9) - 1;
            theta = shfl_u64(skey, l9);
        }
        resolved = ((u32)(theta >> 32) > 0x80000000u) && (theta > k64);
    }

    if (resolved) {
        sel = win; mid = (u32)id;
        return;
    }
    // ---- r6-validated exact fallback over up to 640 candidates ----
    u64 tt[10];
    u64 key = skey, key2 = 0;
#pragma unroll 1
    for (int it = 0; it < 10; it++) {
        if (it > 0) {
            u64 ck = crow[it * 64 + lane];
            u32 hbits = unmono_key((u32)(ck >> 32));
            int id2 = 0xFFFF - (int)(ck & 0xFFFFu);
            int t2 = m - last_sel[id2] - 1; if (t2 > 63) t2 = 63;
            float s2 = __uint_as_float(hbits) * __shfl(tbl_r, t2);
            key = ((u64)mono_key(s2) << 32) | (ck & 0xFFFFu);
            key2 = 0;
#pragma unroll
            for (int rr = 0; rr < 10; rr++) if (lane == rr) key2 = tt[rr];
        }
#pragma unroll
        for (int rr = 0; rr < 10; rr++) {
            u64 mx = (key > key2) ? key : key2;
            u64 wm = wave_max64(mx);
            if (key == wm)  key = 0;
            if (key2 == wm) key2 = 0;
            tt[rr] = wm;
        }
        if (it == 9) break;
        u32 thr = (u32)(tt[9] >> 32);
        u32 headhi = (u32)(crow[(it + 1) * 64] >> 32);
        if (thr > 0x80000000u && thr > headhi) break;
    }
    u64 wk = 0;
#pragma unroll
    for (int rr = 0; rr < 10; rr++) if (lane == rr) wk = tt[rr];
    sel = (lane < 10) && ((u32)(wk >> 32) > 0x80000000u);
    mid = (u32)(0xFFFF - (int)(wk & 0xFFFFu));
}

// ---------------------------------------------------------------------------
// K3 v2: speculative batch + PARALLEL validation. 1 block x 8 waves.
// Spec: wave w computes row m0+w from the batch-start snapshot (r10).
// Parallel collision check: row w stale iff its spec winners intersect spec
// winners of rows i<w (pairwise id compare over <=80 slots). Rows BEFORE the
// first stale row commit in parallel (exact: non-collided winners have
// identical snapshot/true s; collided non-winners only shrink). Rows from the
// first stale onward: r10-validated serial fixup (re-gather last_sel >= m0,
// recompute with row_top10 on current state when stale).
// ---------------------------------------------------------------------------
__global__ __launch_bounds__(512)
void scan_kernel(const u64* __restrict__ cand, float* __restrict__ out) {
    __shared__ int last_sel[DOUT];           // 16 KB
    __shared__ u32 specw[BATCH][16];         // spec winner ids (0xFFFFFFFF pad)
    __shared__ u64 chunk0[BATCH][64];        // spec chunk-0 backup (4 KB)
    __shared__ u64 k64s[BATCH];
    __shared__ u32 staleF[BATCH];
    const int tid  = threadIdx.x;
    const int lane = tid & 63;
    const int w    = tid >> 6;

    for (int j = tid; j < DOUT; j += 512) last_sel[j] = -100000;

    float tbl_r = 0.0f;                      // lane i holds tbl[i]
    {
        float p = 0.0f;
        for (int i = 0; i < 64; i++) {
            if (i == lane) tbl_r = p;
            p = fminf(p + GAMMA, 1.0f);
        }
    }
    const u64 lmask_lt = (lane == 0) ? 0ull : ((1ull << lane) - 1ull);
    __syncthreads();

    u64 cpre = cand[(size_t)w * RQ + lane];
    u64 kpre = cand[(size_t)w * RQ + 64];

    for (int m0 = 0; m0 < NROWS; m0 += BATCH) {
        const int m = m0 + w;
        const u64 c  = cpre;
        const u64 kk = kpre;
        int mp = m + BATCH; if (mp >= NROWS) mp = w;
        cpre = cand[(size_t)mp * RQ + lane];
        kpre = cand[(size_t)mp * RQ + 64];

        // ---- spec phase (8 waves parallel, snapshot state) ----
        bool sel; u32 mid;
        row_top10(m, c, kk, cand + (size_t)m * RQ, last_sel, tbl_r, lane,
                  lmask_lt, sel, mid);

        if (lane < 16) specw[w][lane] = 0xFFFFFFFFu;
        const u64 smask = __ballot(sel);
        const int slot = __popcll(smask & lmask_lt);
        if (sel) specw[w][slot] = mid;
        chunk0[w][lane] = c;
        if (lane == 0) k64s[w] = kk;
        __syncthreads();                                       // B1

        // ---- parallel collision check ----
        u32 my[10];
#pragma unroll
        for (int q = 0; q < 10; q++) my[q] = specw[w][q];      // broadcast reads
        bool hit = false;
#pragma unroll
        for (int pass = 0; pass < 2; pass++) {
            const int e = lane + pass * 64;
            if (e < BATCH * 10) {
                const int i = e / 10, j = e - i * 10;
                if (i < w) {
                    const u32 eid = specw[i][j];
                    if (eid != 0xFFFFFFFFu) {
#pragma unroll
                        for (int q = 0; q < 10; q++) hit |= (eid == my[q]);
                    }
                }
            }
        }
        const u32 st = __ballot(hit) ? 1u : 0u;
        if (lane == 0) staleF[w] = st;
        __syncthreads();                                       // B2

        int firstStale = BATCH;
#pragma unroll
        for (int i = BATCH - 1; i >= 0; i--) if (staleF[i]) firstStale = i;

        // ---- parallel commit of provably-valid prefix ----
        if (w < firstStale && sel) {
            out[(size_t)m * DOUT + mid] = 1.0f;
            last_sel[mid] = m;
        }
        __syncthreads();                                       // B3

        // ---- serial tail (wave 0), r10-validated fixup ----
        if (w == 0 && firstStale < BATCH) {
            for (int i = firstStale; i < BATCH; i++) {
                const int mi = m0 + i;
                const u32 sid = (lane < 10) ? specw[i][lane] : 0xFFFFFFFFu;
                const bool has = (sid != 0xFFFFFFFFu);
                const int ls2 = has ? last_sel[sid] : -100000;
                const u64 stale = __ballot(has && (ls2 >= m0));
                if (stale == 0ull) {
                    if (has) {
                        out[(size_t)mi * DOUT + sid] = 1.0f;
                        last_sel[sid] = mi;
                    }
                } else {
                    bool s2; u32 mid2;
                    row_top10(mi, chunk0[i][lane], k64s[i],
                              cand + (size_t)mi * RQ, last_sel, tbl_r, lane,
                              lmask_lt, s2, mid2);
                    if (s2) {
                        out[(size_t)mi * DOUT + mid2] = 1.0f;
                        last_sel[mid2] = mi;
                    }
                }
            }
        }
        __syncthreads();                                       // B4
    }
}

// ---------------------------------------------------------------------------
extern "C" void kernel_launch(void* const* d_in, const int* in_sizes, int n_in,
                              void* d_out, int out_size, void* d_ws, size_t ws_size,
                              hipStream_t stream) {
    const float* X  = (const float*)d_in[0];   // 8192 x 1024 f32
    const float* Wt = (const float*)d_in[1];   // 4096 x 1024 f32
    const float* b  = (const float*)d_in[2];   // 4096 f32
    // d_in[3] = k == 10 (beacon-verified)
    float* out = (float*)d_out;
    float* H   = (float*)d_ws;                 // 128 MB (beacon-verified)
    (void)in_sizes; (void)n_in; (void)out_size; (void)ws_size;

    gemm_lrelu_f64acc<<<dim3(32, 64), 256, 0, stream>>>(X, Wt, b, H);
    topk640_kernel<<<dim3(NROWS), 256, 0, stream>>>(H);
    hipMemsetAsync(d_out, 0, (size_t)NROWS * DOUT * sizeof(float), stream);
    scan_kernel<<<dim3(1), 512, 0, stream>>>((const u64*)H, out);
}